// Round 2
// baseline (2583.541 us; speedup 1.0000x reference)
//
#include <hip/hip_runtime.h>
#include <math.h>

// Problem constants
#define B_ 16
#define C_ 64
#define H_ 128
#define W_ 128
#define HW_ (H_*W_)
#define OUT_ELEMS 16777216   // B*C*H*W

// Workspace layout (in floats)
#define CHM_OFF   0           // ch_mask: 512
#define WCT_OFF   512         // transposed wc: [256][64] = 16384
#define WT_OFF    16896       // 7 weight sets, each [576][64] = 36864
#define WT_SET    36864
#define FEA_A_OFF 274944
#define FEA_B_OFF (274944 + OUT_ELEMS)

typedef __attribute__((ext_vector_type(16))) float vf16;

// ---------------------------------------------------------------------------
__global__ __launch_bounds__(64) void mask_kernel(
    const float* __restrict__ gum, const float* __restrict__ par,
    float* __restrict__ chm, float* __restrict__ out_tail)
{
    int c = threadIdx.x;  // 0..63
    #pragma unroll
    for (int i = 0; i < 4; ++i) {
        int base = (c*4 + i)*2;
        float g0 = -logf(-logf(gum[base]));
        float g1 = -logf(-logf(gum[base+1]));
        float a0 = par[base] + g0, a1 = par[base+1] + g1;
        float mx = fmaxf(a0, a1);
        float e0 = expf(a0 - mx), e1 = expf(a1 - mx);
        float inv = 1.0f / (e0 + e1);
        float m0 = e0*inv, m1 = e1*inv;
        chm[base] = m0; chm[base+1] = m1;
        out_tail[base] = m0; out_tail[base+1] = m1;
    }
}

// ---------------------------------------------------------------------------
// wt_all[set][k][o], k = ic*9 + ky*3 + kx; set 0=w0, 1/2=w1*md/ms, 3/4=w2, 5/6=w3
// wct[row][o] = wc[o][row]
__global__ __launch_bounds__(256) void prep_kernel(
    const float* __restrict__ w0, const float* __restrict__ w1,
    const float* __restrict__ w2, const float* __restrict__ w3,
    const float* __restrict__ wc, const float* __restrict__ chm,
    float* __restrict__ wt_all, float* __restrict__ wct)
{
    int idx = blockIdx.x*256 + threadIdx.x;
    if (idx < 7*WT_SET) {
        int set = idx / WT_SET;
        int r   = idx % WT_SET;
        int k   = r >> 6;     // 0..575
        int o   = r & 63;
        int ic  = k / 9;
        int k9  = k % 9;
        const float* wsrc = (set == 0) ? w0 : (set <= 2 ? w1 : (set <= 4 ? w2 : w3));
        float v = wsrc[(o*64 + ic)*9 + k9];
        if (set > 0) {
            int stage = (set + 1) >> 1;
            int sel   = (set - 1) & 1;
            v *= chm[(ic*4 + stage)*2 + sel];
        }
        wt_all[idx] = v;
    } else {
        int r2 = idx - 7*WT_SET;
        if (r2 < 256*64) {
            int row = r2 >> 6; int o = r2 & 63;
            wct[row*64 + o] = wc[o*256 + row];
        }
    }
}

// ---------------------------------------------------------------------------
// Direct 3x3 conv, SAME. Block tile: 64 oc x 256 px (two image rows).
// 4 waves; wave w owns oc [16w, 16w+16) -> weight loads are wave-uniform
// (SGPR s_load_dwordx16), FMA uses scalar weight operand. LDS holds only the
// input tile (8 ic x 4 rows x 132). Each lane: 16 oc x 4 px (x2 sets if DUAL).
template<bool DUAL>
__global__ __launch_bounds__(256) void conv_kernel(
    const float* __restrict__ in, const float* __restrict__ wtA,
    const float* __restrict__ wtS, const float* __restrict__ chm,
    const float* __restrict__ spa, float* __restrict__ outFea, int stage)
{
    __shared__ float s_in[8*4*132];   // 16896 B

    const int tid  = threadIdx.x;
    const int wave = __builtin_amdgcn_readfirstlane(tid >> 6);
    const int lane = tid & 63;
    const int oc0  = wave * 16;
    const int r    = lane >> 5;          // which of the 2 output rows
    const int c    = (lane & 31) * 4;    // output col base (4 px)

    const int bid = blockIdx.x;
    const int rp  = bid & 63;            // row pair
    const int b   = bid >> 6;
    const int h0  = rp * 2;

    float accA[16][4];
    float accS[DUAL ? 16 : 1][4];
    #pragma unroll
    for (int j = 0; j < 16; ++j)
        #pragma unroll
        for (int p = 0; p < 4; ++p) { accA[j][p] = 0.f; if (DUAL) accS[j][p] = 0.f; }

    for (int ch = 0; ch < 8; ++ch) {
        const int ic0 = ch * 8;
        __syncthreads();
        // stage input rows h0-1 .. h0+2 (zero-padded), phys col = gw+1
        for (int e = tid; e < 8*4*130; e += 256) {
            int ici = e / 520;
            int rem = e - ici*520;
            int ry  = rem / 130;
            int cc  = rem - ry*130;
            int gh  = h0 - 1 + ry;
            int gw  = cc - 1;
            float v = 0.f;
            if ((unsigned)gh < (unsigned)H_ && (unsigned)gw < (unsigned)W_)
                v = in[((b*C_ + ic0 + ici)*H_ + gh)*W_ + gw];
            s_in[(ici*4 + ry)*132 + cc] = v;
        }
        __syncthreads();

        for (int i = 0; i < 8; ++i) {
            const int kbase = (ic0 + i)*9;
            #pragma unroll
            for (int ky = 0; ky < 3; ++ky) {
                const float* rowp = &s_in[((i<<2) + r + ky)*132 + c];
                float4 v0 = *(const float4*)rowp;
                float2 v1 = *(const float2*)(rowp + 4);
                float vals[6] = {v0.x, v0.y, v0.z, v0.w, v1.x, v1.y};
                #pragma unroll
                for (int kx = 0; kx < 3; ++kx) {
                    const int k = kbase + ky*3 + kx;
                    vf16 wa = *(const vf16*)(wtA + k*64 + oc0);
                    vf16 wsv;
                    if (DUAL) wsv = *(const vf16*)(wtS + k*64 + oc0);
                    #pragma unroll
                    for (int j = 0; j < 16; ++j) {
                        const float wj = wa[j];
                        #pragma unroll
                        for (int p = 0; p < 4; ++p)
                            accA[j][p] = fmaf(wj, vals[kx + p], accA[j][p]);
                        if (DUAL) {
                            const float sj = wsv[j];
                            #pragma unroll
                            for (int p = 0; p < 4; ++p)
                                accS[j][p] = fmaf(sj, vals[kx + p], accS[j][p]);
                        }
                    }
                }
            }
        }
    }

    // epilogue: gating + relu + store
    const int h = h0 + r;
    float4 spav = *(const float4*)&spa[b*HW_ + h*W_ + c];
    float sp[4] = {spav.x, spav.y, spav.z, spav.w};
    #pragma unroll
    for (int j = 0; j < 16; ++j) {
        const int oc = oc0 + j;
        const float md = chm[(oc*4 + stage)*2 + 0];
        const float ms = chm[(oc*4 + stage)*2 + 1];
        float4 rv;
        float* rr = (float*)&rv;
        #pragma unroll
        for (int p = 0; p < 4; ++p) {
            float f = accA[j][p] * (ms*sp[p] + md);
            if (DUAL) f += accS[j][p] * ((ms + md)*sp[p]);
            rr[p] = fmaxf(f, 0.f);
        }
        *(float4*)&outFea[((b*C_ + oc)*H_ + h)*W_ + c] = rv;
    }
}

// ---------------------------------------------------------------------------
// Pointwise 64->64 GEMM: out[b,o,p] (+)= sum_c wct[stage*64+c][o]*fea[b,c,p]
__global__ __launch_bounds__(256) void pw_kernel(
    const float* __restrict__ fea, const float* __restrict__ wslice,
    const float* __restrict__ bc, float* __restrict__ out, int first)
{
    __shared__ float s_w[64*64];
    __shared__ float s_f[64*64];
    const int tid = threadIdx.x;
    const int bid = blockIdx.x;
    const int w0 = (bid & 1) * 64;
    const int h  = (bid >> 1) & 127;
    const int b  = bid >> 8;
    const int oc0 = (tid >> 4) * 4;
    const int px0 = (tid & 15) * 4;

    for (int v4 = tid; v4 < 1024; v4 += 256)
        ((float4*)s_w)[v4] = ((const float4*)wslice)[v4];
    {
        const int base = b*C_*HW_ + h*W_ + w0;
        for (int v4 = tid; v4 < 1024; v4 += 256) {
            int c = v4 >> 4; int w4 = v4 & 15;
            ((float4*)s_f)[v4] = *(const float4*)&fea[base + c*HW_ + w4*4];
        }
    }
    __syncthreads();

    float acc[4][4] = {{0.f}};
    #pragma unroll 4
    for (int c = 0; c < 64; ++c) {
        float4 wv = *(const float4*)&s_w[c*64 + oc0];
        float4 xv = *(const float4*)&s_f[c*64 + px0];
        const float xs[4]  = {xv.x, xv.y, xv.z, xv.w};
        const float wsv[4] = {wv.x, wv.y, wv.z, wv.w};
        #pragma unroll
        for (int o = 0; o < 4; ++o)
            #pragma unroll
            for (int p = 0; p < 4; ++p)
                acc[o][p] += wsv[o]*xs[p];
    }

    #pragma unroll
    for (int o = 0; o < 4; ++o) {
        int oc = oc0 + o;
        float* op = &out[((b*C_ + oc)*H_ + h)*W_ + w0 + px0];
        float4 r;
        if (first) {
            float bias = bc[oc];
            r.x = acc[o][0]+bias; r.y = acc[o][1]+bias;
            r.z = acc[o][2]+bias; r.w = acc[o][3]+bias;
        } else {
            float4 prev = *(const float4*)op;
            r.x = prev.x+acc[o][0]; r.y = prev.y+acc[o][1];
            r.z = prev.z+acc[o][2]; r.w = prev.w+acc[o][3];
        }
        *(float4*)op = r;
    }
}

// ---------------------------------------------------------------------------
extern "C" void kernel_launch(void* const* d_in, const int* in_sizes, int n_in,
                              void* d_out, int out_size, void* d_ws, size_t ws_size,
                              hipStream_t stream)
{
    const float* x0  = (const float*)d_in[0];
    const float* spa = (const float*)d_in[1];
    const float* gum = (const float*)d_in[2];
    const float* par = (const float*)d_in[3];
    const float* w0  = (const float*)d_in[4];
    const float* w1  = (const float*)d_in[5];
    const float* w2  = (const float*)d_in[6];
    const float* w3  = (const float*)d_in[7];
    const float* wc  = (const float*)d_in[8];
    const float* bc  = (const float*)d_in[9];
    float* out = (float*)d_out;
    float* ws  = (float*)d_ws;

    float* chm  = ws + CHM_OFF;
    float* wct  = ws + WCT_OFF;
    float* wt   = ws + WT_OFF;
    float* feaA = ws + FEA_A_OFF;
    float* feaB = ws + FEA_B_OFF;

    mask_kernel<<<1, 64, 0, stream>>>(gum, par, chm, out + OUT_ELEMS);
    prep_kernel<<<1072, 256, 0, stream>>>(w0, w1, w2, w3, wc, chm, wt, wct);

    // stage 0
    conv_kernel<false><<<1024, 256, 0, stream>>>(x0, wt, nullptr, chm, spa, feaA, 0);
    pw_kernel<<<4096, 256, 0, stream>>>(feaA, wct + 0*4096, bc, out, 1);

    // stage 1
    conv_kernel<true><<<1024, 256, 0, stream>>>(feaA, wt + 1*WT_SET, wt + 2*WT_SET, chm, spa, feaB, 1);
    pw_kernel<<<4096, 256, 0, stream>>>(feaB, wct + 1*4096, bc, out, 0);

    // stage 2
    conv_kernel<true><<<1024, 256, 0, stream>>>(feaB, wt + 3*WT_SET, wt + 4*WT_SET, chm, spa, feaA, 2);
    pw_kernel<<<4096, 256, 0, stream>>>(feaA, wct + 2*4096, bc, out, 0);

    // stage 3
    conv_kernel<true><<<1024, 256, 0, stream>>>(feaA, wt + 5*WT_SET, wt + 6*WT_SET, chm, spa, feaB, 3);
    pw_kernel<<<4096, 256, 0, stream>>>(feaB, wct + 3*4096, bc, out, 0);
}

// Round 3
// 1573.540 us; speedup vs baseline: 1.6419x; 1.6419x over previous
//
#include <hip/hip_runtime.h>
#include <math.h>

// Problem constants
#define B_ 16
#define C_ 64
#define H_ 128
#define W_ 128
#define HW_ (H_*W_)
#define OUT_ELEMS 16777216   // B*C*H*W

// Workspace layout (floats)
#define CHM_OFF   0            // 512
#define WCT_OFF   512          // 16384
#define AH_OFF    16896        // 258048 ushort = 129024 floats
#define AL_OFF    145920       // 258048 ushort
#define FEA_A_OFF 274944
#define FEA_B_OFF (274944 + OUT_ELEMS)

// A-image ushort bases per stage
#define A_S0   0
#define A_S(s) (36864 + ((s)-1)*73728)   // s = 1..3

typedef __attribute__((ext_vector_type(4))) short  v4s;
typedef __attribute__((ext_vector_type(8))) short  v8s;
typedef __attribute__((ext_vector_type(4))) float  v4f;

__device__ __forceinline__ ushort f2bf(float f) {
    unsigned u = __builtin_bit_cast(unsigned, f);
    unsigned r = u + 0x7FFFu + ((u >> 16) & 1u);
    return (ushort)(r >> 16);
}
__device__ __forceinline__ float bf2f(ushort h) {
    unsigned u = ((unsigned)h) << 16;
    return __builtin_bit_cast(float, u);
}
__device__ __forceinline__ v8s ld_frag(const ushort* p) {  // p is 8B-aligned
    v4s a = *(const v4s*)(const void*)p;
    v4s b = *(const v4s*)(const void*)(p + 4);
    return __builtin_shufflevector(a, b, 0, 1, 2, 3, 4, 5, 6, 7);
}

// ---------------------------------------------------------------------------
__global__ __launch_bounds__(64) void mask_kernel(
    const float* __restrict__ gum, const float* __restrict__ par,
    float* __restrict__ chm, float* __restrict__ out_tail)
{
    int c = threadIdx.x;
    #pragma unroll
    for (int i = 0; i < 4; ++i) {
        int base = (c*4 + i)*2;
        float g0 = -logf(-logf(gum[base]));
        float g1 = -logf(-logf(gum[base+1]));
        float a0 = par[base] + g0, a1 = par[base+1] + g1;
        float mx = fmaxf(a0, a1);
        float e0 = expf(a0 - mx), e1 = expf(a1 - mx);
        float inv = 1.0f / (e0 + e1);
        float m0 = e0*inv, m1 = e1*inv;
        chm[base] = m0; chm[base+1] = m1;
        out_tail[base] = m0; out_tail[base+1] = m1;
    }
}

// ---------------------------------------------------------------------------
// Build bf16 hi/lo A-images (gate-folded, frag-friendly layout) + wct.
// Stage0:  AH[A_S0 + ((c*9+t)*64 + oc)*32 + icl]        (plain w0)
// Stage s: AH[A_S(s) + ((c*9+t)*128 + ocM)*32 + icl], ocM = 2*oc + set,
//          value = w_s[oc][ic][t] * chm[(ic*4+s)*2+set]   (ic = input-ch gate)
__global__ __launch_bounds__(256) void prep_kernel(
    const float* __restrict__ w0, const float* __restrict__ w1,
    const float* __restrict__ w2, const float* __restrict__ w3,
    const float* __restrict__ wc, const float* __restrict__ chm,
    ushort* __restrict__ AH, ushort* __restrict__ AL, float* __restrict__ wct)
{
    int idx = blockIdx.x*256 + threadIdx.x;
    if (idx < 258048) {
        float v;
        if (idx < 36864) {
            int c  = idx / 18432;
            int r2 = idx % 18432;
            int t  = r2 / 2048;
            int r3 = r2 % 2048;
            int oc = r3 >> 5, icl = r3 & 31;
            int ic = c*32 + icl;
            v = w0[(oc*64 + ic)*9 + t];
        } else {
            int j  = idx - 36864;
            int s  = 1 + j / 73728;
            int r  = j % 73728;
            int c  = r / 36864;
            int r2 = r % 36864;
            int t  = r2 / 4096;
            int r3 = r2 % 4096;
            int ocM = r3 >> 5, icl = r3 & 31;
            int ic = c*32 + icl;
            int oc = ocM >> 1, set = ocM & 1;
            const float* wsrc = (s == 1) ? w1 : (s == 2 ? w2 : w3);
            v = wsrc[(oc*64 + ic)*9 + t] * chm[(ic*4 + s)*2 + set];
        }
        ushort hi = f2bf(v);
        ushort lo = f2bf(v - bf2f(hi));
        AH[idx] = hi;
        AL[idx] = lo;
    } else {
        int r2 = idx - 258048;
        if (r2 < 16384) {
            int row = r2 >> 6, o = r2 & 63;
            wct[row*64 + o] = wc[o*256 + row];
        }
    }
}

// ---------------------------------------------------------------------------
// MFMA conv. Block = one (b,h) output row, 128 px. M = 64*NSETS (ocM).
// 256 threads = 4 waves in 2(M) x 2(N). 3-term split-bf16 accumulation.
template<int NSETS>
__global__ __launch_bounds__(256, 2) void conv_mfma(
    const float* __restrict__ in, const ushort* __restrict__ Ahi,
    const ushort* __restrict__ Alo, const float* __restrict__ chm,
    const float* __restrict__ spa, float* __restrict__ outFea, int stage)
{
    constexpr int MOC = 64*NSETS;
    constexpr int MT  = MOC/32;    // Mtiles per wave (wave covers MOC/2)
    constexpr int ICP = 36;

    __shared__ __align__(16) ushort sBh[3*130*ICP];
    __shared__ __align__(16) ushort sBl[3*130*ICP];
    __shared__ __align__(16) ushort sAh[MOC*ICP];
    __shared__ __align__(16) ushort sAl[MOC*ICP];

    const int tid  = threadIdx.x;
    const int u    = blockIdx.x;
    const int xcd  = u & 7;
    const int slot = u >> 3;
    const int b    = slot >> 4;
    const int h    = xcd*16 + (slot & 15);

    const int lane = tid & 63;
    const int wave = tid >> 6;
    const int wrow = wave >> 1;       // M half
    const int wcol = wave & 1;        // N half
    const int q    = lane >> 4;
    const int ln16 = lane & 15;

    v4f acc[MT][4];
    #pragma unroll
    for (int m = 0; m < MT; ++m)
        #pragma unroll
        for (int n = 0; n < 4; ++n) acc[m][n] = (v4f){0.f, 0.f, 0.f, 0.f};

    for (int c = 0; c < 2; ++c) {
        const int ic0 = c*32;
        __syncthreads();
        // ---- stage B (hi/lo bf16, transposed [row][col][ic]) ----
        for (int e = tid; e < 12480; e += 256) {
            int ic  = e / 390;
            int rem = e - ic*390;
            int row = rem / 130;
            int col = rem - row*130;
            int gh = h - 1 + row;
            int gw = col - 1;
            float v = 0.f;
            if ((unsigned)gh < (unsigned)H_ && (unsigned)gw < (unsigned)W_)
                v = in[((b*C_ + ic0 + ic)*H_ + gh)*W_ + gw];
            ushort hi = f2bf(v);
            ushort lo = f2bf(v - bf2f(hi));
            int a = (row*130 + col)*ICP + ic;
            sBh[a] = hi; sBl[a] = lo;
        }
        for (int t = 0; t < 9; ++t) {
            if (t) __syncthreads();
            // ---- stage A(chunk, tap): MOC x 32 hi/lo, packed u32 pairs ----
            {
                const unsigned* gh32 = (const unsigned*)(const void*)(Ahi + (c*9 + t)*MOC*32);
                const unsigned* gl32 = (const unsigned*)(const void*)(Alo + (c*9 + t)*MOC*32);
                for (int e2 = tid; e2 < MOC*16; e2 += 256) {
                    int oc  = e2 >> 4;
                    int icp = e2 & 15;
                    unsigned vh = gh32[e2];
                    unsigned vl = gl32[e2];
                    *(unsigned*)(void*)&sAh[oc*ICP + icp*2] = vh;
                    *(unsigned*)(void*)&sAl[oc*ICP + icp*2] = vl;
                }
            }
            __syncthreads();
            const int ky = t / 3, kx = t - ky*3;
            // A frags (hoisted across n-tiles)
            v8s ah[MT], al[MT];
            #pragma unroll
            for (int m = 0; m < MT; ++m) {
                int ocM = wrow*(MOC/2) + m*16 + ln16;
                int aa = ocM*ICP + q*8;
                ah[m] = ld_frag(&sAh[aa]);
                al[m] = ld_frag(&sAl[aa]);
            }
            #pragma unroll
            for (int n = 0; n < 4; ++n) {
                int col = wcol*64 + n*16 + ln16 + kx;   // staged col = px + kx
                int ba = (ky*130 + col)*ICP + q*8;
                v8s bh = ld_frag(&sBh[ba]);
                v8s bl = ld_frag(&sBl[ba]);
                #pragma unroll
                for (int m = 0; m < MT; ++m) {
                    acc[m][n] = __builtin_amdgcn_mfma_f32_16x16x32_bf16(ah[m], bh, acc[m][n], 0, 0, 0);
                    acc[m][n] = __builtin_amdgcn_mfma_f32_16x16x32_bf16(ah[m], bl, acc[m][n], 0, 0, 0);
                    acc[m][n] = __builtin_amdgcn_mfma_f32_16x16x32_bf16(al[m], bh, acc[m][n], 0, 0, 0);
                }
            }
        }
    }

    // ---- epilogue: gates + relu, fp32 store ----
    const float* spaRow = &spa[b*HW_ + h*W_];
    #pragma unroll
    for (int n = 0; n < 4; ++n) {
        int px = wcol*64 + n*16 + ln16;
        float sp = spaRow[px];
        #pragma unroll
        for (int m = 0; m < MT; ++m) {
            if constexpr (NSETS == 2) {
                #pragma unroll
                for (int rp = 0; rp < 2; ++rp) {
                    int oc = wrow*32 + m*8 + q*2 + rp;
                    float aD = acc[m][n][rp*2 + 0];
                    float aS = acc[m][n][rp*2 + 1];
                    float md = chm[(oc*4 + stage)*2 + 0];
                    float ms = chm[(oc*4 + stage)*2 + 1];
                    float f = aD*(ms*sp + md) + aS*((ms + md)*sp);
                    outFea[((b*C_ + oc)*H_ + h)*W_ + px] = fmaxf(f, 0.f);
                }
            } else {
                #pragma unroll
                for (int r = 0; r < 4; ++r) {
                    int oc = wrow*32 + m*16 + q*4 + r;
                    float md = chm[(oc*4 + stage)*2 + 0];
                    float ms = chm[(oc*4 + stage)*2 + 1];
                    float f = acc[m][n][r]*(ms*sp + md);
                    outFea[((b*C_ + oc)*H_ + h)*W_ + px] = fmaxf(f, 0.f);
                }
            }
        }
    }
}

// ---------------------------------------------------------------------------
// Pointwise 64->64 GEMM (fp32 VALU, unchanged)
__global__ __launch_bounds__(256) void pw_kernel(
    const float* __restrict__ fea, const float* __restrict__ wslice,
    const float* __restrict__ bc, float* __restrict__ out, int first)
{
    __shared__ float s_w[64*64];
    __shared__ float s_f[64*64];
    const int tid = threadIdx.x;
    const int bid = blockIdx.x;
    const int w0 = (bid & 1) * 64;
    const int h  = (bid >> 1) & 127;
    const int b  = bid >> 8;
    const int oc0 = (tid >> 4) * 4;
    const int px0 = (tid & 15) * 4;

    for (int v4 = tid; v4 < 1024; v4 += 256)
        ((float4*)s_w)[v4] = ((const float4*)wslice)[v4];
    {
        const int base = b*C_*HW_ + h*W_ + w0;
        for (int v4 = tid; v4 < 1024; v4 += 256) {
            int c = v4 >> 4; int w4 = v4 & 15;
            ((float4*)s_f)[v4] = *(const float4*)&fea[base + c*HW_ + w4*4];
        }
    }
    __syncthreads();

    float acc[4][4] = {{0.f}};
    #pragma unroll 4
    for (int c = 0; c < 64; ++c) {
        float4 wv = *(const float4*)&s_w[c*64 + oc0];
        float4 xv = *(const float4*)&s_f[c*64 + px0];
        const float xs[4]  = {xv.x, xv.y, xv.z, xv.w};
        const float wsv[4] = {wv.x, wv.y, wv.z, wv.w};
        #pragma unroll
        for (int o = 0; o < 4; ++o)
            #pragma unroll
            for (int p = 0; p < 4; ++p)
                acc[o][p] += wsv[o]*xs[p];
    }

    #pragma unroll
    for (int o = 0; o < 4; ++o) {
        int oc = oc0 + o;
        float* op = &out[((b*C_ + oc)*H_ + h)*W_ + w0 + px0];
        float4 r;
        if (first) {
            float bias = bc[oc];
            r.x = acc[o][0]+bias; r.y = acc[o][1]+bias;
            r.z = acc[o][2]+bias; r.w = acc[o][3]+bias;
        } else {
            float4 prev = *(const float4*)op;
            r.x = prev.x+acc[o][0]; r.y = prev.y+acc[o][1];
            r.z = prev.z+acc[o][2]; r.w = prev.w+acc[o][3];
        }
        *(float4*)op = r;
    }
}

// ---------------------------------------------------------------------------
extern "C" void kernel_launch(void* const* d_in, const int* in_sizes, int n_in,
                              void* d_out, int out_size, void* d_ws, size_t ws_size,
                              hipStream_t stream)
{
    const float* x0  = (const float*)d_in[0];
    const float* spa = (const float*)d_in[1];
    const float* gum = (const float*)d_in[2];
    const float* par = (const float*)d_in[3];
    const float* w0  = (const float*)d_in[4];
    const float* w1  = (const float*)d_in[5];
    const float* w2  = (const float*)d_in[6];
    const float* w3  = (const float*)d_in[7];
    const float* wc  = (const float*)d_in[8];
    const float* bc  = (const float*)d_in[9];
    float* out = (float*)d_out;
    float* ws  = (float*)d_ws;

    float*  chm  = ws + CHM_OFF;
    float*  wct  = ws + WCT_OFF;
    ushort* AH   = (ushort*)(void*)(ws + AH_OFF);
    ushort* AL   = (ushort*)(void*)(ws + AL_OFF);
    float*  feaA = ws + FEA_A_OFF;
    float*  feaB = ws + FEA_B_OFF;

    mask_kernel<<<1, 64, 0, stream>>>(gum, par, chm, out + OUT_ELEMS);
    prep_kernel<<<1072, 256, 0, stream>>>(w0, w1, w2, w3, wc, chm, AH, AL, wct);

    // stage 0
    conv_mfma<1><<<2048, 256, 0, stream>>>(x0, AH + A_S0, AL + A_S0, chm, spa, feaA, 0);
    pw_kernel<<<4096, 256, 0, stream>>>(feaA, wct + 0*4096, bc, out, 1);

    // stage 1
    conv_mfma<2><<<2048, 256, 0, stream>>>(feaA, AH + A_S(1), AL + A_S(1), chm, spa, feaB, 1);
    pw_kernel<<<4096, 256, 0, stream>>>(feaB, wct + 1*4096, bc, out, 0);

    // stage 2
    conv_mfma<2><<<2048, 256, 0, stream>>>(feaB, AH + A_S(2), AL + A_S(2), chm, spa, feaA, 2);
    pw_kernel<<<4096, 256, 0, stream>>>(feaA, wct + 2*4096, bc, out, 0);

    // stage 3
    conv_mfma<2><<<2048, 256, 0, stream>>>(feaA, AH + A_S(3), AL + A_S(3), chm, spa, feaB, 3);
    pw_kernel<<<4096, 256, 0, stream>>>(feaB, wct + 3*4096, bc, out, 0);
}

// Round 4
// 721.841 us; speedup vs baseline: 3.5791x; 2.1799x over previous
//
#include <hip/hip_runtime.h>
#include <math.h>

// Problem constants
#define B_ 16
#define C_ 64
#define H_ 128
#define W_ 128
#define HW_ (H_*W_)
#define OUT_ELEMS 16777216   // B*C*H*W

// Workspace byte offsets
#define CHM_B    0                      // 512 f32
#define PWA_B    2048                   // 16384 u16
#define AH_B     34816                  // 258048 u16
#define FEA_B(s) (550912u + (size_t)(s)*33554432u)  // 4 x 16777216 u16

// A-image u16 offsets within AH
#define A_S0   0
#define A_S(s) (36864 + ((s)-1)*73728)  // s = 1..3

typedef __attribute__((ext_vector_type(4))) short  v4s;
typedef __attribute__((ext_vector_type(8))) short  v8s;
typedef __attribute__((ext_vector_type(4))) float  v4f;

__device__ __forceinline__ ushort f2bf(float f) {
    unsigned u = __builtin_bit_cast(unsigned, f);
    unsigned r = u + 0x7FFFu + ((u >> 16) & 1u);
    return (ushort)(r >> 16);
}
__device__ __forceinline__ v8s ld_b64x2(const ushort* p) {  // 8B-aligned
    v4s a = *(const v4s*)(const void*)p;
    v4s b = *(const v4s*)(const void*)(p + 4);
    return __builtin_shufflevector(a, b, 0, 1, 2, 3, 4, 5, 6, 7);
}

// ---------------------------------------------------------------------------
__global__ __launch_bounds__(64) void mask_kernel(
    const float* __restrict__ gum, const float* __restrict__ par,
    float* __restrict__ chm, float* __restrict__ out_tail)
{
    int c = threadIdx.x;
    #pragma unroll
    for (int i = 0; i < 4; ++i) {
        int base = (c*4 + i)*2;
        float g0 = -logf(-logf(gum[base]));
        float g1 = -logf(-logf(gum[base+1]));
        float a0 = par[base] + g0, a1 = par[base+1] + g1;
        float mx = fmaxf(a0, a1);
        float e0 = expf(a0 - mx), e1 = expf(a1 - mx);
        float inv = 1.0f / (e0 + e1);
        float m0 = e0*inv, m1 = e1*inv;
        chm[base] = m0; chm[base+1] = m1;
        out_tail[base] = m0; out_tail[base+1] = m1;
    }
}

// ---------------------------------------------------------------------------
// Build bf16 A-images (gate-folded weights) + bf16 pw weights.
// Stage0:  AH[A_S0 + ((c*9+t)*64 + oc)*32 + icl]
// Stage s: AH[A_S(s) + ((c*9+t)*128 + ocM)*32 + icl], ocM = 2*oc + set
__global__ __launch_bounds__(256) void prep_kernel(
    const float* __restrict__ w0, const float* __restrict__ w1,
    const float* __restrict__ w2, const float* __restrict__ w3,
    const float* __restrict__ wc, const float* __restrict__ chm,
    ushort* __restrict__ AH, ushort* __restrict__ pwA)
{
    int idx = blockIdx.x*256 + threadIdx.x;   // < 274432
    if (idx < 36864) {
        int blk = idx >> 11;            // c*9+t, 0..17
        int r3  = idx & 2047;
        int oc = r3 >> 5, icl = r3 & 31;
        int cc = blk / 9, t = blk - 9*cc;
        int ic = cc*32 + icl;
        AH[idx] = f2bf(w0[(oc*64 + ic)*9 + t]);
    } else if (idx < 258048) {
        int j = idx - 36864;
        int s = 1 + j / 73728;
        int r = j % 73728;
        int blk = r >> 12;              // 0..17
        int r3  = r & 4095;
        int ocM = r3 >> 5, icl = r3 & 31;
        int cc = blk / 9, t = blk - 9*cc;
        int ic = cc*32 + icl;
        int oc = ocM >> 1, set = ocM & 1;
        const float* wsrc = (s == 1) ? w1 : (s == 2 ? w2 : w3);
        AH[idx] = f2bf(wsrc[(oc*64 + ic)*9 + t] * chm[(ic*4 + s)*2 + set]);
    } else {
        int r = idx - 258048;           // < 16384
        pwA[r] = f2bf(wc[r]);
    }
}

// ---------------------------------------------------------------------------
// MFMA conv, pure bf16. Block = one (b,h) row, 128 px. M = 64*NSETS rows
// (dense/sparse interleaved ocM = 2*oc+set). 4 waves as 2(M) x 2(N).
// B tile (input row triplet, [row][col][ic] stride 36) in LDS per 32-ic chunk.
// A frags stream L2 -> registers (coalesced dwordx4), pipelined 1 tap ahead.
// No barriers inside the 9-tap loop.
template<int NSETS, bool INF32>
__global__ __launch_bounds__(256, 2) void conv_bf16(
    const void* __restrict__ inv, const ushort* __restrict__ A,
    const float* __restrict__ chm, const float* __restrict__ spa,
    ushort* __restrict__ feaOut, int stage)
{
    constexpr int MOC = 64*NSETS;
    constexpr int MT  = MOC/32;     // m-tiles per wave
    __shared__ ushort sB[3*130*36]; // 28080 B

    const int tid  = threadIdx.x;
    const int lane = tid & 63, wave = tid >> 6;
    const int wrow = wave >> 1, wcol = wave & 1;
    const int q = lane >> 4, ln16 = lane & 15;
    const int h = blockIdx.x & 127, b = blockIdx.x >> 7;

    v4f acc[MT][4];
    #pragma unroll
    for (int m = 0; m < MT; ++m)
        #pragma unroll
        for (int n = 0; n < 4; ++n) acc[m][n] = (v4f){0.f, 0.f, 0.f, 0.f};

    int aRow[MT];
    #pragma unroll
    for (int m = 0; m < MT; ++m)
        aRow[m] = (wrow*(MOC/2) + m*16 + ln16)*32 + q*8;

    for (int c = 0; c < 2; ++c) {
        const int ic0 = c*32;
        __syncthreads();
        for (int e = tid; e < 12480; e += 256) {
            int ic  = e / 390;
            int rem = e - ic*390;
            int ry  = rem / 130;
            int cc  = rem - ry*130;
            int gh = h - 1 + ry, gw = cc - 1;
            ushort v = 0;
            if ((unsigned)gh < 128u && (unsigned)gw < 128u) {
                size_t gi = (size_t)((b*C_ + ic0 + ic)*H_ + gh)*W_ + gw;
                v = INF32 ? f2bf(((const float*)inv)[gi]) : ((const ushort*)inv)[gi];
            }
            sB[(ry*130 + cc)*36 + ic] = v;
        }
        __syncthreads();

        const ushort* Ab = A + c*9*MOC*32;
        v8s af[MT];
        #pragma unroll
        for (int m = 0; m < MT; ++m)
            af[m] = *(const v8s*)(const void*)(Ab + aRow[m]);

        #pragma unroll
        for (int t = 0; t < 9; ++t) {
            v8s afn[MT];
            if (t < 8) {
                #pragma unroll
                for (int m = 0; m < MT; ++m)
                    afn[m] = *(const v8s*)(const void*)(Ab + (t+1)*MOC*32 + aRow[m]);
            }
            const int ky = t/3, kx = t - 3*(t/3);
            #pragma unroll
            for (int nt = 0; nt < 4; ++nt) {
                int col = wcol*64 + nt*16 + ln16 + kx;
                v8s bf = ld_b64x2(&sB[(ky*130 + col)*36 + q*8]);
                #pragma unroll
                for (int m = 0; m < MT; ++m)
                    acc[m][nt] = __builtin_amdgcn_mfma_f32_16x16x32_bf16(af[m], bf, acc[m][nt], 0, 0, 0);
            }
            if (t < 8) {
                #pragma unroll
                for (int m = 0; m < MT; ++m) af[m] = afn[m];
            }
        }
    }

    // epilogue: gates + relu, bf16 store
    const float* spaRow = &spa[b*HW_ + h*W_];
    #pragma unroll
    for (int nt = 0; nt < 4; ++nt) {
        int px = wcol*64 + nt*16 + ln16;
        float sp = spaRow[px];
        #pragma unroll
        for (int m = 0; m < MT; ++m) {
            if constexpr (NSETS == 2) {
                #pragma unroll
                for (int rp = 0; rp < 2; ++rp) {
                    int oc = wrow*32 + m*8 + q*2 + rp;
                    float md = chm[(oc*4 + stage)*2 + 0];
                    float ms = chm[(oc*4 + stage)*2 + 1];
                    float f = acc[m][nt][2*rp]*(ms*sp + md)
                            + acc[m][nt][2*rp+1]*((ms + md)*sp);
                    feaOut[((size_t)(b*C_ + oc)*H_ + h)*W_ + px] = f2bf(fmaxf(f, 0.f));
                }
            } else {
                #pragma unroll
                for (int r = 0; r < 4; ++r) {
                    int oc = wrow*32 + m*16 + q*4 + r;
                    float md = chm[(oc*4 + stage)*2 + 0];
                    float ms = chm[(oc*4 + stage)*2 + 1];
                    float f = acc[m][nt][r]*(ms*sp + md);
                    feaOut[((size_t)(b*C_ + oc)*H_ + h)*W_ + px] = f2bf(fmaxf(f, 0.f));
                }
            }
        }
    }
}

// ---------------------------------------------------------------------------
// Final pointwise: out[b,o,px] = sum_{k=0..255} wc[o][k]*fea_{k/64}[k%64][px] + bc[o]
// Block = 64 px of one (b,h) row. MFMA: M=64, N=64, K=256.
__global__ __launch_bounds__(256, 2) void pw_final(
    const ushort* __restrict__ fea, const ushort* __restrict__ pwA,
    const float* __restrict__ bc, float* __restrict__ out)
{
    __shared__ ushort sF[64*260];   // 33280 B, [px][k] stride 260

    const int tid  = threadIdx.x;
    const int lane = tid & 63, wave = tid >> 6;
    const int wrow = wave >> 1, wcol = wave & 1;
    const int q = lane >> 4, ln16 = lane & 15;
    const int half = blockIdx.x & 1;
    const int h = (blockIdx.x >> 1) & 127;
    const int b = blockIdx.x >> 8;
    const int px0 = half*64;

    for (int e = tid; e < 16384; e += 256) {
        int s  = e >> 12;
        int r  = e & 4095;
        int ic = r >> 6, px = r & 63;
        sF[px*260 + s*64 + ic] =
            fea[(size_t)s*OUT_ELEMS + ((size_t)(b*C_ + ic)*H_ + h)*W_ + px0 + px];
    }
    __syncthreads();

    v4f acc[2][2];
    #pragma unroll
    for (int m = 0; m < 2; ++m)
        #pragma unroll
        for (int n = 0; n < 2; ++n) acc[m][n] = (v4f){0.f, 0.f, 0.f, 0.f};

    #pragma unroll
    for (int ks = 0; ks < 8; ++ks) {
        v8s a[2];
        #pragma unroll
        for (int m = 0; m < 2; ++m)
            a[m] = *(const v8s*)(const void*)(pwA + (wrow*32 + m*16 + ln16)*256 + ks*32 + q*8);
        #pragma unroll
        for (int n = 0; n < 2; ++n) {
            int px = wcol*32 + n*16 + ln16;
            v8s bf = ld_b64x2(&sF[px*260 + ks*32 + q*8]);
            #pragma unroll
            for (int m = 0; m < 2; ++m)
                acc[m][n] = __builtin_amdgcn_mfma_f32_16x16x32_bf16(a[m], bf, acc[m][n], 0, 0, 0);
        }
    }

    #pragma unroll
    for (int n = 0; n < 2; ++n) {
        int px = px0 + wcol*32 + n*16 + ln16;
        #pragma unroll
        for (int m = 0; m < 2; ++m)
            #pragma unroll
            for (int r = 0; r < 4; ++r) {
                int o = wrow*32 + m*16 + q*4 + r;
                out[((size_t)(b*C_ + o)*H_ + h)*W_ + px] = acc[m][n][r] + bc[o];
            }
    }
}

// ---------------------------------------------------------------------------
extern "C" void kernel_launch(void* const* d_in, const int* in_sizes, int n_in,
                              void* d_out, int out_size, void* d_ws, size_t ws_size,
                              hipStream_t stream)
{
    const float* x0  = (const float*)d_in[0];
    const float* spa = (const float*)d_in[1];
    const float* gum = (const float*)d_in[2];
    const float* par = (const float*)d_in[3];
    const float* w0  = (const float*)d_in[4];
    const float* w1  = (const float*)d_in[5];
    const float* w2  = (const float*)d_in[6];
    const float* w3  = (const float*)d_in[7];
    const float* wc  = (const float*)d_in[8];
    const float* bc  = (const float*)d_in[9];
    float* out = (float*)d_out;
    char*  ws  = (char*)d_ws;

    float*  chm = (float*)(ws + CHM_B);
    ushort* pwA = (ushort*)(ws + PWA_B);
    ushort* AH  = (ushort*)(ws + AH_B);
    ushort* fea0 = (ushort*)(ws + FEA_B(0));
    ushort* fea1 = (ushort*)(ws + FEA_B(1));
    ushort* fea2 = (ushort*)(ws + FEA_B(2));
    ushort* fea3 = (ushort*)(ws + FEA_B(3));

    mask_kernel<<<1, 64, 0, stream>>>(gum, par, chm, out + OUT_ELEMS);
    prep_kernel<<<1072, 256, 0, stream>>>(w0, w1, w2, w3, wc, chm, AH, pwA);

    conv_bf16<1, true ><<<2048, 256, 0, stream>>>(x0,   AH + A_S0,  chm, spa, fea0, 0);
    conv_bf16<2, false><<<2048, 256, 0, stream>>>(fea0, AH + A_S(1), chm, spa, fea1, 1);
    conv_bf16<2, false><<<2048, 256, 0, stream>>>(fea1, AH + A_S(2), chm, spa, fea2, 2);
    conv_bf16<2, false><<<2048, 256, 0, stream>>>(fea2, AH + A_S(3), chm, spa, fea3, 3);

    pw_final<<<4096, 256, 0, stream>>>(fea0, pwA, bc, out);
}